// Round 6
// baseline (463.105 us; speedup 1.0000x reference)
//
#include <hip/hip_runtime.h>
#include <hip/hip_bf16.h>
#include <math.h>

#define B_ 32
#define N_ 128
#define L_ 1024
#define DD_ 256
#define TD_ 1280
#define HID_ 512
#define H_ 8
#define HD_ 64

// ws layout (float offsets)
#define WS_D    0
#define WS_RM   (WS_D   + 2097152)
#define WS_RIZ  (WS_RM  + 32768)
#define WS_RMT  (WS_RIZ + 32768)
#define WS_RZT  (WS_RMT + 524288)
#define WS_RWT  (WS_RZT + 524288)
#define WS_CNT  (WS_RWT + 524288)
#define WS_WT   (WS_CNT + 64)
#define WS_THB  (WS_WT  + 327680)
#define WS_DWB  (WS_THB + 8388608)

using bf16x8 = __attribute__((ext_vector_type(8))) short;
using u16x4 = __attribute__((ext_vector_type(4))) unsigned short;
using floatx4 = __attribute__((ext_vector_type(4))) float;

static __device__ __forceinline__ unsigned short f2bf(float f) {
  unsigned int u = __float_as_uint(f);
  unsigned int r = (u + 0x7FFFu + ((u >> 16) & 1u)) >> 16;
  return (unsigned short)r;
}
static __device__ __forceinline__ float bf2f(unsigned short s) {
  return __uint_as_float(((unsigned int)s) << 16);
}
// async global->LDS DMA, 16 B per lane; LDS dest = wave-uniform base + lane*16.
static __device__ __forceinline__ void gload16(const void* g, void* l) {
  __builtin_amdgcn_global_load_lds(
      (const __attribute__((address_space(1))) void*)g,
      (__attribute__((address_space(3))) void*)l, 16, 0, 0);
}

// ---------------------------------------------------------------------------
// K0: per-batch valid counts (detect int32 vs packed-bool at runtime).
// ---------------------------------------------------------------------------
__global__ __launch_bounds__(256) void count_kernel(const int* __restrict__ dmask,
                                                    const int* __restrict__ tmask,
                                                    int* __restrict__ cnts) {
  __shared__ int red[256];
  const int b = blockIdx.x, tid = threadIdx.x;
  const bool dint = (dmask[0] == 1);
  const bool tint = (tmask[0] == 1);
  int s = 0;
  if (dint) {
    for (int i = tid; i < N_; i += 256) s += (dmask[(size_t)b*N_ + i] != 0);
  } else {
    const unsigned char* p = (const unsigned char*)dmask;
    for (int i = tid; i < N_; i += 256) s += (p[(size_t)b*N_ + i] != 0);
  }
  red[tid] = s; __syncthreads();
  for (int off = 128; off > 0; off >>= 1) { if (tid < off) red[tid] += red[tid+off]; __syncthreads(); }
  if (tid == 0) cnts[b*2] = red[0];
  __syncthreads();
  s = 0;
  if (tint) {
    for (int i = tid; i < L_; i += 256) s += (tmask[(size_t)b*L_ + i] != 0);
  } else {
    const unsigned char* p = (const unsigned char*)tmask;
    for (int i = tid; i < L_; i += 256) s += (p[(size_t)b*L_ + i] != 0);
  }
  red[tid] = s; __syncthreads();
  for (int off = 128; off > 0; off >>= 1) { if (tid < off) red[tid] += red[tid+off]; __syncthreads(); }
  if (tid == 0) cnts[b*2+1] = red[0];
}

// ---------------------------------------------------------------------------
// K0b: W (KxN fp32) -> WT (NxK bf16), 32x32 LDS tiles.
// ---------------------------------------------------------------------------
__global__ __launch_bounds__(256) void transpose_bf16_kernel(
    const float* __restrict__ W, unsigned short* __restrict__ WT, int K, int Nd) {
  __shared__ float tile[32][33];
  const int tid = threadIdx.x;
  const int n0 = blockIdx.x * 32, k0 = blockIdx.y * 32;
  const int c = tid & 31, r0 = tid >> 5;
#pragma unroll
  for (int i = 0; i < 4; i++) {
    const int r = r0 + i * 8;
    tile[c][r] = W[(size_t)(k0 + r) * Nd + n0 + c];
  }
  __syncthreads();
#pragma unroll
  for (int i = 0; i < 4; i++) {
    const int r = r0 + i * 8;
    WT[(size_t)(n0 + r) * K + k0 + c] = f2bf(tile[r][c]);
  }
}

// ---------------------------------------------------------------------------
// K1: t-projection, fused fp32->bf16, BM=128 x BN=256 (round-5 tile) with
// COVERED-DRAIN schedule: Bs double-buffered (As single), both prefetches
// issued BEFORE the MFMA phase so barrier-1's implicit vmcnt(0) drain is
// covered by ~2500 cyc of compute; awrite runs between barriers with vmcnt
// already 0; barrier-2 is a pure sync (no vm ops outstanding). Round-5
// exposed ~300-700 cyc of B-DMA latency per K-step at barrier-2.
// LDS = 16K(As) + 2x32K(Bs) = 80 KB -> 2 blocks/CU (VGPR-capped there anyway).
// ---------------------------------------------------------------------------
__global__ __launch_bounds__(256, 2) void gemm_t_mfma_kernel(
    const float* __restrict__ A, const unsigned short* __restrict__ WT,
    const float* __restrict__ bias, unsigned short* __restrict__ thb, int K) {
  __shared__ __align__(16) unsigned short As[8192];       // 128 rows x 64 k
  __shared__ __align__(16) unsigned short Bs[2][16384];   // 256 rows x 64 k, dbuf
  const int tid = threadIdx.x;
  const int lin = blockIdx.x;
  const int xcd = lin & 7, sq = lin >> 3;
  const int n_t = sq & 1, m_t = (sq >> 1) + xcd * 32;
  const int m0 = m_t * 128, n0 = n_t * 256;
  const int lane = tid & 63, wave = tid >> 6;
  const int wm = wave & 1, wn = wave >> 1;
  const int quad = lane >> 4, lrow = lane & 15;

  floatx4 acc[4][8];
#pragma unroll
  for (int i = 0; i < 4; i++)
#pragma unroll
    for (int j = 0; j < 8; j++) acc[i][j] = (floatx4){0.f, 0.f, 0.f, 0.f};

  // B staging source offsets (four calls x two kgroups; 256 rows)
  int srcoffB[4][2];
#pragma unroll
  for (int call = 0; call < 4; call++) {
    const int i = call * 256 + tid;
    const int r = i >> 2;
    const int c = (i & 3) ^ ((r >> 1) & 3);
#pragma unroll
    for (int g = 0; g < 2; g++) srcoffB[call][g] = r * K + g * 32 + c * 8;
  }

  // A staging map (coalesced): instr i covers rows i*16 + arow_ (4 rows/wave),
  // lane's 16-lane group spans one row's 64 contiguous floats.
  const int arow_ = wave * 4 + (lane >> 4);   // base row 0..15
  const int x_ = lane & 15;                    // 16-B column slot (x_*4 floats)
  const int ag_ = x_ >> 3;                     // kgroup 0/1
  const int acq_ = (x_ & 7) >> 1;              // 8-col chunk within group
  const int ahalf_ = x_ & 1;                   // half-slot (4 shorts)

  const float* Abase = A + (size_t)m0 * K;
  const unsigned short* Bbase = WT + (size_t)n0 * K;

  float4 apf[8];

  auto aload = [&](int k0) {
#pragma unroll
    for (int i = 0; i < 8; i++)
      apf[i] = *(const float4*)(Abase + (size_t)(i * 16 + arow_) * K + k0 + x_ * 4);
  };
  auto awrite = [&]() {
#pragma unroll
    for (int i = 0; i < 8; i++) {
      const int r = i * 16 + arow_;
      const int sw = (r >> 1) & 3;
      u16x4 p;
      p[0] = f2bf(apf[i].x); p[1] = f2bf(apf[i].y);
      p[2] = f2bf(apf[i].z); p[3] = f2bf(apf[i].w);
      *(u16x4*)&As[ag_ * 4096 + (r * 4 + (acq_ ^ sw)) * 8 + ahalf_ * 4] = p;
    }
  };
  auto bstage = [&](int buf, int k0) {
#pragma unroll
    for (int g = 0; g < 2; g++)
#pragma unroll
      for (int call = 0; call < 4; call++) {
        const int dst = g * 8192 + (call * 256 + wave * 64) * 8;
        gload16(Bbase + k0 + srcoffB[call][g], &Bs[buf][dst]);
      }
  };

  const int nkt = K / 64;   // 20

  // prologue (one exposed drain, unavoidable)
  aload(0);
  bstage(0, 0);
  awrite();                 // waits apf(0)
  __syncthreads();          // drains B-DMA(0); As/Bs[0] visible

  int cur = 0;
  for (int t = 0; t < nkt; t++) {
    const int nxt = cur ^ 1;
    if (t + 1 < nkt) {
      aload((t + 1) * 64);            // in flight across MFMA phase
      bstage(nxt, (t + 1) * 64);      // in flight across MFMA phase
    }
#pragma unroll
    for (int g = 0; g < 2; g++) {
      bf16x8 afr[4];
#pragma unroll
      for (int i = 0; i < 4; i++) {
        const int ar = wm * 64 + i * 16 + lrow;
        afr[i] = *(const bf16x8*)&As[g * 4096 + (ar * 4 + (quad ^ ((ar >> 1) & 3))) * 8];
      }
#pragma unroll
      for (int jh = 0; jh < 2; jh++) {
        bf16x8 bfr[4];
#pragma unroll
        for (int j = 0; j < 4; j++) {
          const int br = wn * 128 + (jh * 4 + j) * 16 + lrow;
          bfr[j] = *(const bf16x8*)&Bs[cur][g * 8192 + (br * 4 + (quad ^ ((br >> 1) & 3))) * 8];
        }
#pragma unroll
        for (int i = 0; i < 4; i++)
#pragma unroll
          for (int j = 0; j < 4; j++)
            acc[i][jh * 4 + j] = __builtin_amdgcn_mfma_f32_16x16x32_bf16(
                afr[i], bfr[j], acc[i][jh * 4 + j], 0, 0, 0);
      }
    }
    __syncthreads();        // drains apf+DMA(t+1), covered by MFMAs; fences As reads
    if (t + 1 < nkt) {
      awrite();             // As <- tile t+1; vmcnt already 0 -> pure VALU+ds_write
    }
    __syncthreads();        // As(t+1) visible; nothing outstanding -> cheap
    cur = nxt;
  }

  float bj[8];
#pragma unroll
  for (int j = 0; j < 8; j++) bj[j] = bias[n0 + wn * 128 + j * 16 + lrow];
#pragma unroll
  for (int i = 0; i < 4; i++) {
#pragma unroll
    for (int j = 0; j < 8; j++) {
      const int gcol = n0 + wn * 128 + j * 16 + lrow;
      const int hh = gcol >> 6, e = gcol & 63;
#pragma unroll
      for (int r = 0; r < 4; r++) {
        const int grow = m0 + wm * 64 + i * 16 + quad * 4 + r;
        const int bb = grow >> 10, l = grow & 1023;
        thb[(((size_t)bb * H_ + hh) * L_ + l) * HD_ + e] = f2bf(acc[i][j][r] + bj[j]);
      }
    }
  }
}

// ---------------------------------------------------------------------------
// K2: fp32 GEMM for the small d-projection (keeps dproj exact for ctx_t).
// ---------------------------------------------------------------------------
__global__ __launch_bounds__(256) void gemm_bias_kernel(
    const float* __restrict__ A, const float* __restrict__ W,
    const float* __restrict__ bias, float* __restrict__ C,
    int M, int K, int Nd) {
  __shared__ float As[8][132];
  __shared__ float Bs[8][132];
  const int tid = threadIdx.x;
  const int m0 = blockIdx.y * 128, n0 = blockIdx.x * 128;
  const int lr = tid >> 1, lc = (tid & 1) * 4;
  const int wr = tid >> 5, wc = (tid & 31) * 4;
  const int tm = (tid >> 4) * 4, tn = (tid & 15) * 4;

  float acc[2][2][4][4];
#pragma unroll
  for (int a = 0; a < 2; a++)
#pragma unroll
    for (int bq = 0; bq < 2; bq++)
#pragma unroll
      for (int i = 0; i < 4; i++)
#pragma unroll
        for (int j = 0; j < 4; j++) acc[a][bq][i][j] = 0.f;

  const float* Aptr = A + (size_t)(m0 + lr) * K + lc;
  const float* Wptr = W + (size_t)wr * Nd + n0 + wc;

  for (int k0 = 0; k0 < K; k0 += 8) {
    float4 a4 = *(const float4*)(Aptr + k0);
    float4 w4 = *(const float4*)(Wptr + (size_t)k0 * Nd);
    __syncthreads();
    As[lc+0][lr] = a4.x; As[lc+1][lr] = a4.y; As[lc+2][lr] = a4.z; As[lc+3][lr] = a4.w;
    *(float4*)&Bs[wr][wc] = w4;
    __syncthreads();
#pragma unroll
    for (int kk = 0; kk < 8; kk++) {
      float4 a0 = *(const float4*)&As[kk][tm];
      float4 a1 = *(const float4*)&As[kk][tm + 64];
      float4 b0 = *(const float4*)&Bs[kk][tn];
      float4 b1 = *(const float4*)&Bs[kk][tn + 64];
      const float av0[4] = {a0.x, a0.y, a0.z, a0.w};
      const float av1[4] = {a1.x, a1.y, a1.z, a1.w};
      const float bv0[4] = {b0.x, b0.y, b0.z, b0.w};
      const float bv1[4] = {b1.x, b1.y, b1.z, b1.w};
#pragma unroll
      for (int i = 0; i < 4; i++)
#pragma unroll
        for (int j = 0; j < 4; j++) {
          acc[0][0][i][j] += av0[i] * bv0[j];
          acc[0][1][i][j] += av0[i] * bv1[j];
          acc[1][0][i][j] += av1[i] * bv0[j];
          acc[1][1][i][j] += av1[i] * bv1[j];
        }
    }
  }
  float4 bias0 = *(const float4*)&bias[n0 + tn];
  float4 bias1 = *(const float4*)&bias[n0 + tn + 64];
  const float bb0[4] = {bias0.x, bias0.y, bias0.z, bias0.w};
  const float bb1[4] = {bias1.x, bias1.y, bias1.z, bias1.w};
#pragma unroll
  for (int mh = 0; mh < 2; mh++)
#pragma unroll
    for (int i = 0; i < 4; i++) {
      const int row = m0 + mh * 64 + tm + i;
      float* cp = C + (size_t)row * Nd + n0;
      float4 o0, o1;
      o0.x = acc[mh][0][i][0] + bb0[0]; o0.y = acc[mh][0][i][1] + bb0[1];
      o0.z = acc[mh][0][i][2] + bb0[2]; o0.w = acc[mh][0][i][3] + bb0[3];
      o1.x = acc[mh][1][i][0] + bb1[0]; o1.y = acc[mh][1][i][1] + bb1[1];
      o1.z = acc[mh][1][i][2] + bb1[2]; o1.w = acc[mh][1][i][3] + bb1[3];
      *(float4*)(cp + tn) = o0;
      *(float4*)(cp + tn + 64) = o1;
    }
}

// ---------------------------------------------------------------------------
// K3: dWb[b][h][n][e] = (dh @ Wb[h]) in bf16. grid = 256 (hb = b*8+h).
// v6: stage the 128x64 dproj slice in LDS (coalesced float4) -- removes 64
// uncoalesced per-thread scalar GLOBAL loads; wb reads as explicit float4.
// ---------------------------------------------------------------------------
__global__ __launch_bounds__(256) void dw_kernel(
    const float* __restrict__ dproj, const float* __restrict__ Wb,
    unsigned short* __restrict__ dWb) {
  __shared__ float wb_s[64 * 64];    // 16 KB
  __shared__ float dp_s[128 * 64];   // 32 KB
  const int tid = threadIdx.x;
  const int hb = blockIdx.x, b = hb >> 3, h = hb & 7;
  for (int i = tid; i < 4096; i += 256) wb_s[i] = Wb[(size_t)h * 4096 + i];
#pragma unroll
  for (int rep = 0; rep < 8; rep++) {   // 2048 float4 loads, 16 threads/row
    const int idx = rep * 256 + tid;
    const int row = idx >> 4, c4 = (idx & 15) * 4;
    *(float4*)&dp_s[row * 64 + c4] =
        *(const float4*)&dproj[((size_t)(b * N_ + row)) * HID_ + h * HD_ + c4];
  }
  __syncthreads();
  const int n = tid >> 1, half = tid & 1;
  float acc[32];
#pragma unroll
  for (int e = 0; e < 32; e++) acc[e] = 0.f;
  const float* dpr = &dp_s[n * 64];
  for (int k = 0; k < 64; k++) {
    const float a = dpr[k];   // 2 threads share addr -> LDS broadcast
    const float* wr = &wb_s[k * 64 + half * 32];
#pragma unroll
    for (int e4 = 0; e4 < 8; e4++) {
      float4 w = *(const float4*)&wr[e4 * 4];
      acc[e4*4+0] += a * w.x; acc[e4*4+1] += a * w.y;
      acc[e4*4+2] += a * w.z; acc[e4*4+3] += a * w.w;
    }
  }
  unsigned short* outp = dWb + ((size_t)hb * N_ + n) * HD_ + half * 32;
#pragma unroll
  for (int e = 0; e < 32; e++) outp[e] = f2bf(acc[e]);
}

// ---------------------------------------------------------------------------
// S-tile (128n x 64l) via MFMA, operands from global bf16 head-major arrays;
// masked fp32 S to LDS (stride 69: conflict-light on row and column walks).
// ---------------------------------------------------------------------------
__device__ __forceinline__ void mfma_S_tile(
    const unsigned short* __restrict__ thp, const unsigned short* __restrict__ dwp,
    float* __restrict__ S_s, int ncnt, int lv, int tid) {
  const int lane = tid & 63, wave = tid >> 6;
  const int quad = lane >> 4, lr = lane & 15;
  const int noff = (wave & 1) * 64, loff = (wave >> 1) * 32;

  floatx4 acc[4][2];
#pragma unroll
  for (int i = 0; i < 4; i++)
#pragma unroll
    for (int j = 0; j < 2; j++) acc[i][j] = (floatx4){0.f, 0.f, 0.f, 0.f};

#pragma unroll
  for (int kc = 0; kc < 2; kc++) {
    bf16x8 bfr[2];
#pragma unroll
    for (int j = 0; j < 2; j++)
      bfr[j] = *(const bf16x8*)&thp[(size_t)(loff + j * 16 + lr) * HD_ + kc * 32 + quad * 8];
#pragma unroll
    for (int i = 0; i < 4; i++) {
      bf16x8 afr = *(const bf16x8*)&dwp[(size_t)(noff + i * 16 + lr) * HD_ + kc * 32 + quad * 8];
#pragma unroll
      for (int j = 0; j < 2; j++)
        acc[i][j] = __builtin_amdgcn_mfma_f32_16x16x32_bf16(afr, bfr[j], acc[i][j], 0, 0, 0);
    }
  }
#pragma unroll
  for (int i = 0; i < 4; i++)
#pragma unroll
    for (int j = 0; j < 2; j++)
#pragma unroll
      for (int r = 0; r < 4; r++) {
        const int n = noff + i * 16 + quad * 4 + r;
        const int li = loff + j * 16 + lr;
        const bool ok = (n < ncnt) && (li < lv);
        S_s[n * 69 + li] = ok ? acc[i][j][r] : -1e9f;
      }
}

// ---------------------------------------------------------------------------
// K4: per (hb, lt): S tile -> column softmax (complete per tile); per-tile
// row stats (m_t, z_t) and per-tile w partial (no atomics). grid = 256*16.
// v6: n-loops capped at block-uniform ncnt (rows >= ncnt contribute exactly
// 0: exp(-1e9 - cm) underflows to 0) -- identical results, ~25% fewer
// exp+LDS ops on average (ncnt in [64,128]).
// ---------------------------------------------------------------------------
__global__ __launch_bounds__(256, 4) void attn_stats_kernel(
    const unsigned short* __restrict__ thb, const unsigned short* __restrict__ dWb,
    const int* __restrict__ cnts, float* __restrict__ rwt,
    float* __restrict__ rmt, float* __restrict__ rzt) {
  __shared__ float S_s[128 * 69];
  __shared__ float red[256];
  __shared__ float zb_s[256], wb_s[256];
  __shared__ float cm_s[64], ics_s[64];
  const int tid = threadIdx.x;
  const int hb = blockIdx.x >> 4, lt = blockIdx.x & 15;
  const int b = hb >> 3;
  const int ncnt = cnts[b * 2], lcnt = cnts[b * 2 + 1];
  const int l0g = lt * 64;
  if (l0g >= lcnt) return;
  const int lv = min(64, lcnt - l0g);

  mfma_S_tile(thb + ((size_t)hb * L_ + l0g) * HD_, dWb + (size_t)hb * N_ * HD_,
              S_s, ncnt, lv, tid);
  __syncthreads();

  {  // column max partials (over valid n only)
    const int l = tid & 63, q = tid >> 6;
    const int ne = min(q * 32 + 32, ncnt);
    float pm = -INFINITY;
    for (int n = q * 32; n < ne; n++) pm = fmaxf(pm, S_s[n * 69 + l]);
    red[tid] = pm;
  }
  __syncthreads();
  if (tid < 64)
    cm_s[tid] = fmaxf(fmaxf(red[tid], red[tid + 64]), fmaxf(red[tid + 128], red[tid + 192]));
  __syncthreads();
  {  // column expsum partials (valid n only)
    const int l = tid & 63, q = tid >> 6;
    const int ne = min(q * 32 + 32, ncnt);
    const float cm = cm_s[l];
    float ps = 0.f;
    for (int n = q * 32; n < ne; n++) ps += __expf(S_s[n * 69 + l] - cm);
    red[tid] = ps;
  }
  __syncthreads();
  if (tid < 64)
    ics_s[tid] = 1.f / (red[tid] + red[tid + 64] + red[tid + 128] + red[tid + 192]);
  __syncthreads();
  {  // row pass, split across halves: n = tid&127, half covers 32 l's
    const int n = tid & 127, half = tid >> 7;
    const float* Sr = &S_s[n * 69];
    const int lb = half * 32, le = min(lb + 32, lv);
    float tmax = -INFINITY;
    for (int l = lb; l < le; l++) tmax = fmaxf(tmax, Sr[l]);
    red[tid] = tmax;
    __syncthreads();
    const float tm = fmaxf(red[n], red[n + 128]);
    float z = 0.f, w = 0.f;
    for (int l = lb; l < le; l++) {
      const float s = Sr[l];
      z += __expf(s - tm);
      w += __expf(s - cm_s[l]) * ics_s[l];
    }
    zb_s[tid] = z; wb_s[tid] = w;
    __syncthreads();
    if (tid < 128) {
      const size_t o = ((size_t)hb * 16 + lt) * 128 + tid;
      rmt[o] = tm;
      rzt[o] = zb_s[tid] + zb_s[tid + 128];
      rwt[o] = wb_s[tid] + wb_s[tid + 128];
    }
  }
}

// ---------------------------------------------------------------------------
// K5: combine per-tile row stats -> (m, 1/Z) and w; finalize ctx_t. grid=256.
// ---------------------------------------------------------------------------
__global__ __launch_bounds__(256) void attn_combine_kernel(
    const float* __restrict__ rmt, const float* __restrict__ rzt,
    const float* __restrict__ rwt, const float* __restrict__ dproj,
    const int* __restrict__ cnts, float* __restrict__ rm_g,
    float* __restrict__ riz_g, float* __restrict__ outp) {
  __shared__ float red[256];
  __shared__ float w_s[128];
  const int tid = threadIdx.x;
  const int hb = blockIdx.x, b = hb >> 3, h = hb & 7;
  const int ncnt = cnts[b * 2], lcnt = cnts[b * 2 + 1];
  const int ntl = (lcnt + 63) >> 6;
  if (tid < 128) {
    const int n = tid;
    float m = -INFINITY;
    for (int t = 0; t < ntl; t++)
      m = fmaxf(m, rmt[((size_t)hb * 16 + t) * 128 + n]);
    float Z = 0.f, w = 0.f;
    for (int t = 0; t < ntl; t++) {
      const size_t o = ((size_t)hb * 16 + t) * 128 + n;
      Z += rzt[o] * __expf(rmt[o] - m);
      w += rwt[o];
    }
    rm_g[hb * 128 + n] = m;
    riz_g[hb * 128 + n] = (n < ncnt) ? 1.f / Z : 0.f;
    w_s[n] = (n < ncnt) ? w : 0.f;
  }
  __syncthreads();
  const int e = tid & 63, q = tid >> 6;
  float p = 0.f;
  const int nb = q * 32, ne = min(nb + 32, ncnt);
  for (int n = nb; n < ne; n++)
    p += w_s[n] * dproj[((size_t)(b * N_ + n)) * HID_ + h * HD_ + e];
  red[tid] = p;
  __syncthreads();
  if (tid < 64) {
    const float s = red[tid] + red[tid + 64] + red[tid + 128] + red[tid + 192];
    outp[(size_t)b * (2 * HID_) + HID_ + h * HD_ + tid] = s / (float)lcnt;
  }
}

// ---------------------------------------------------------------------------
// K6: recompute S tile; v[l] = sum_n exp(S-m[n])/Z[n]; fused ctx_d partial
// accumulation (atomicAdd into zero-initialized out). grid = 256*16.
// v6: n-loop capped at ncnt (riz=0 beyond -> identical); l-loop capped at lv.
// ---------------------------------------------------------------------------
__global__ __launch_bounds__(256, 4) void attn_v_kernel(
    const unsigned short* __restrict__ thb, const unsigned short* __restrict__ dWb,
    const int* __restrict__ cnts, const float* __restrict__ rm_g,
    const float* __restrict__ riz_g, float* __restrict__ outp) {
  __shared__ float S_s[128 * 69];
  __shared__ float red[256];
  __shared__ float rm_s[128], riz_s[128], v_s[64];
  const int tid = threadIdx.x;
  const int hb = blockIdx.x >> 4, lt = blockIdx.x & 15;
  const int b = hb >> 3, h = hb & 7;
  const int ncnt = cnts[b * 2], lcnt = cnts[b * 2 + 1];
  const int l0g = lt * 64;
  if (l0g >= lcnt) return;
  const int lv = min(64, lcnt - l0g);

  if (tid < 128) {
    rm_s[tid] = rm_g[hb * 128 + tid];
    riz_s[tid] = riz_g[hb * 128 + tid];
  }
  const unsigned short* thp = thb + ((size_t)hb * L_ + l0g) * HD_;
  mfma_S_tile(thp, dWb + (size_t)hb * N_ * HD_, S_s, ncnt, lv, tid);
  __syncthreads();

  {
    const int l = tid & 63, q = tid >> 6;
    const int ne = min(q * 32 + 32, ncnt);
    float vp = 0.f;
    for (int n = q * 32; n < ne; n++)
      vp += __expf(S_s[n * 69 + l] - rm_s[n]) * riz_s[n];
    red[tid] = vp;
  }
  __syncthreads();
  const float incnt = 1.f / (float)ncnt;
  if (tid < 64) {
    const float v = (tid < lv)
        ? (red[tid] + red[tid + 64] + red[tid + 128] + red[tid + 192]) * incnt
        : 0.f;
    v_s[tid] = v;
  }
  __syncthreads();
  {  // fused ctx_d partial: sum_{l in tile} v[l] * th[l][e]
    const int e = tid & 63, q = tid >> 6;
    const int le = min(q * 16 + 16, lv);
    float p = 0.f;
    for (int l = q * 16; l < le; l++)
      p += v_s[l] * bf2f(thp[(size_t)l * HD_ + e]);
    red[tid] = p;
  }
  __syncthreads();
  if (tid < 64) {
    const float s = red[tid] + red[tid + 64] + red[tid + 128] + red[tid + 192];
    if (s != 0.f)
      atomicAdd(&outp[(size_t)b * (2 * HID_) + h * HD_ + tid], s);
  }
}

// ---------------------------------------------------------------------------
extern "C" void kernel_launch(void* const* d_in, const int* in_sizes, int n_in,
                              void* d_out, int out_size, void* d_ws, size_t ws_size,
                              hipStream_t stream) {
  const float* drug = (const float*)d_in[0];
  const int* dmask = (const int*)d_in[1];
  const float* tseq = (const float*)d_in[2];
  const int* tmask = (const int*)d_in[3];
  const float* Wd = (const float*)d_in[4];
  const float* bd = (const float*)d_in[5];
  const float* Wt = (const float*)d_in[6];
  const float* bt = (const float*)d_in[7];
  const float* Wb = (const float*)d_in[8];
  float* out = (float*)d_out;
  float* ws = (float*)d_ws;

  float* dp = ws + WS_D;
  float* rm = ws + WS_RM;
  float* riz = ws + WS_RIZ;
  float* rmt = ws + WS_RMT;
  float* rzt = ws + WS_RZT;
  float* rwt = ws + WS_RWT;
  int* cnts = (int*)(ws + WS_CNT);
  unsigned short* wtT = (unsigned short*)(ws + WS_WT);
  unsigned short* thb = (unsigned short*)(ws + WS_THB);
  unsigned short* dWb = (unsigned short*)(ws + WS_DWB);

  count_kernel<<<B_, 256, 0, stream>>>(dmask, tmask, cnts);
  hipMemsetAsync(out, 0, (size_t)out_size * sizeof(float), stream);
  transpose_bf16_kernel<<<dim3(HID_ / 32, TD_ / 32), 256, 0, stream>>>(Wt, wtT, TD_, HID_);
  gemm_t_mfma_kernel<<<(HID_ / 256) * ((B_ * L_) / 128), 256, 0, stream>>>(
      tseq, wtT, bt, thb, TD_);
  gemm_bias_kernel<<<dim3(HID_ / 128, (B_ * N_) / 128), 256, 0, stream>>>(
      drug, Wd, bd, dp, B_ * N_, DD_, HID_);
  dw_kernel<<<B_ * H_, 256, 0, stream>>>(dp, Wb, dWb);
  attn_stats_kernel<<<B_ * H_ * 16, 256, 0, stream>>>(thb, dWb, cnts, rwt, rmt, rzt);
  attn_combine_kernel<<<B_ * H_, 256, 0, stream>>>(rmt, rzt, rwt, dp, cnts, rm, riz, out);
  attn_v_kernel<<<B_ * H_ * 16, 256, 0, stream>>>(thb, dWb, cnts, rm, riz, out);
}

// Round 7
// 452.001 us; speedup vs baseline: 1.0246x; 1.0246x over previous
//
#include <hip/hip_runtime.h>
#include <hip/hip_bf16.h>
#include <math.h>

#define B_ 32
#define N_ 128
#define L_ 1024
#define DD_ 256
#define TD_ 1280
#define HID_ 512
#define H_ 8
#define HD_ 64

// ws layout (float offsets)
#define WS_D    0
#define WS_RM   (WS_D   + 2097152)
#define WS_RIZ  (WS_RM  + 32768)
#define WS_RMT  (WS_RIZ + 32768)
#define WS_RZT  (WS_RMT + 524288)
#define WS_RWT  (WS_RZT + 524288)
#define WS_CNT  (WS_RWT + 524288)
#define WS_WT   (WS_CNT + 64)
#define WS_THB  (WS_WT  + 327680)
#define WS_DWB  (WS_THB + 8388608)

using bf16x8 = __attribute__((ext_vector_type(8))) short;
using u16x4 = __attribute__((ext_vector_type(4))) unsigned short;
using floatx4 = __attribute__((ext_vector_type(4))) float;

static __device__ __forceinline__ unsigned short f2bf(float f) {
  unsigned int u = __float_as_uint(f);
  unsigned int r = (u + 0x7FFFu + ((u >> 16) & 1u)) >> 16;
  return (unsigned short)r;
}
static __device__ __forceinline__ float bf2f(unsigned short s) {
  return __uint_as_float(((unsigned int)s) << 16);
}
// async global->LDS DMA, 16 B per lane; LDS dest = wave-uniform base + lane*16.
static __device__ __forceinline__ void gload16(const void* g, void* l) {
  __builtin_amdgcn_global_load_lds(
      (const __attribute__((address_space(1))) void*)g,
      (__attribute__((address_space(3))) void*)l, 16, 0, 0);
}

// ---------------------------------------------------------------------------
// K0: per-batch valid counts (detect int32 vs packed-bool at runtime).
// ---------------------------------------------------------------------------
__global__ __launch_bounds__(256) void count_kernel(const int* __restrict__ dmask,
                                                    const int* __restrict__ tmask,
                                                    int* __restrict__ cnts) {
  __shared__ int red[256];
  const int b = blockIdx.x, tid = threadIdx.x;
  const bool dint = (dmask[0] == 1);
  const bool tint = (tmask[0] == 1);
  int s = 0;
  if (dint) {
    for (int i = tid; i < N_; i += 256) s += (dmask[(size_t)b*N_ + i] != 0);
  } else {
    const unsigned char* p = (const unsigned char*)dmask;
    for (int i = tid; i < N_; i += 256) s += (p[(size_t)b*N_ + i] != 0);
  }
  red[tid] = s; __syncthreads();
  for (int off = 128; off > 0; off >>= 1) { if (tid < off) red[tid] += red[tid+off]; __syncthreads(); }
  if (tid == 0) cnts[b*2] = red[0];
  __syncthreads();
  s = 0;
  if (tint) {
    for (int i = tid; i < L_; i += 256) s += (tmask[(size_t)b*L_ + i] != 0);
  } else {
    const unsigned char* p = (const unsigned char*)tmask;
    for (int i = tid; i < L_; i += 256) s += (p[(size_t)b*L_ + i] != 0);
  }
  red[tid] = s; __syncthreads();
  for (int off = 128; off > 0; off >>= 1) { if (tid < off) red[tid] += red[tid+off]; __syncthreads(); }
  if (tid == 0) cnts[b*2+1] = red[0];
}

// ---------------------------------------------------------------------------
// K0b: W (KxN fp32) -> WT (NxK bf16), 32x32 LDS tiles.
// ---------------------------------------------------------------------------
__global__ __launch_bounds__(256) void transpose_bf16_kernel(
    const float* __restrict__ W, unsigned short* __restrict__ WT, int K, int Nd) {
  __shared__ float tile[32][33];
  const int tid = threadIdx.x;
  const int n0 = blockIdx.x * 32, k0 = blockIdx.y * 32;
  const int c = tid & 31, r0 = tid >> 5;
#pragma unroll
  for (int i = 0; i < 4; i++) {
    const int r = r0 + i * 8;
    tile[c][r] = W[(size_t)(k0 + r) * Nd + n0 + c];
  }
  __syncthreads();
#pragma unroll
  for (int i = 0; i < 4; i++) {
    const int r = r0 + i * 8;
    WT[(size_t)(n0 + r) * K + k0 + c] = f2bf(tile[r][c]);
  }
}

// ---------------------------------------------------------------------------
// K1: t-projection, fused fp32->bf16. ROUND-5 EXACT config (best measured:
// <98us): BM=128 x BN=256, 4 waves, acc[4][8], single Bs buffer, 48 KB LDS
// -> 3 blocks/CU. Latency-bound regime -> occupancy is the stall-hiding
// mechanism; round-6's 80KB dbuf variant (2 blocks/CU) measured 105us.
// 2-barrier schedule: top barrier drains apf (issued one MFMA-phase ago),
// bstage+awrite between barriers, aload(t+1) issued at top of MFMA phase.
// ---------------------------------------------------------------------------
__global__ __launch_bounds__(256, 2) void gemm_t_mfma_kernel(
    const float* __restrict__ A, const unsigned short* __restrict__ WT,
    const float* __restrict__ bias, unsigned short* __restrict__ thb, int K) {
  __shared__ __align__(16) unsigned short As[8192];    // 128 rows x 64 k
  __shared__ __align__(16) unsigned short Bs[16384];   // 256 rows x 64 k
  const int tid = threadIdx.x;
  const int lin = blockIdx.x;
  const int xcd = lin & 7, sq = lin >> 3;
  const int n_t = sq & 1, m_t = (sq >> 1) + xcd * 32;
  const int m0 = m_t * 128, n0 = n_t * 256;
  const int lane = tid & 63, wave = tid >> 6;
  const int wm = wave & 1, wn = wave >> 1;
  const int quad = lane >> 4, lrow = lane & 15;

  floatx4 acc[4][8];
#pragma unroll
  for (int i = 0; i < 4; i++)
#pragma unroll
    for (int j = 0; j < 8; j++) acc[i][j] = (floatx4){0.f, 0.f, 0.f, 0.f};

  // B staging source offsets (four calls x two kgroups; 256 rows)
  int srcoffB[4][2];
#pragma unroll
  for (int call = 0; call < 4; call++) {
    const int i = call * 256 + tid;
    const int r = i >> 2;
    const int c = (i & 3) ^ ((r >> 1) & 3);
#pragma unroll
    for (int g = 0; g < 2; g++) srcoffB[call][g] = r * K + g * 32 + c * 8;
  }

  // A staging map (coalesced): instr i covers rows i*16 + arow_ (4 rows/wave),
  // lane's 16-lane group spans one row's 64 contiguous floats.
  const int arow_ = wave * 4 + (lane >> 4);   // base row 0..15
  const int x_ = lane & 15;                    // 16-B column slot (x_*4 floats)
  const int ag_ = x_ >> 3;                     // kgroup 0/1
  const int acq_ = (x_ & 7) >> 1;              // 8-col chunk within group
  const int ahalf_ = x_ & 1;                   // half-slot (4 shorts)

  const float* Abase = A + (size_t)m0 * K;
  const unsigned short* Bbase = WT + (size_t)n0 * K;

  float4 apf[8];

  auto aload = [&](int k0) {
#pragma unroll
    for (int i = 0; i < 8; i++)
      apf[i] = *(const float4*)(Abase + (size_t)(i * 16 + arow_) * K + k0 + x_ * 4);
  };
  auto awrite = [&]() {
#pragma unroll
    for (int i = 0; i < 8; i++) {
      const int r = i * 16 + arow_;
      const int sw = (r >> 1) & 3;
      u16x4 p;
      p[0] = f2bf(apf[i].x); p[1] = f2bf(apf[i].y);
      p[2] = f2bf(apf[i].z); p[3] = f2bf(apf[i].w);
      *(u16x4*)&As[ag_ * 4096 + (r * 4 + (acq_ ^ sw)) * 8 + ahalf_ * 4] = p;
    }
  };
  auto bstage = [&](int k0) {
#pragma unroll
    for (int g = 0; g < 2; g++)
#pragma unroll
      for (int call = 0; call < 4; call++) {
        const int dst = g * 8192 + (call * 256 + wave * 64) * 8;
        gload16(Bbase + k0 + srcoffB[call][g], &Bs[dst]);
      }
  };

  const int nkt = K / 64;   // 20
  aload(0);

  for (int t = 0; t < nkt; t++) {
    __syncthreads();        // all waves done with As/Bs(t-1); drains apf loads
    bstage(t * 64);         // B DMA issue (8 gload16)
    awrite();               // As <- cvt(apf); apf older than DMA in vmcnt FIFO
    __syncthreads();        // drains B DMA; As/Bs(t) visible
    if (t + 1 < nkt) aload((t + 1) * 64);   // in flight across MFMA phase
#pragma unroll
    for (int g = 0; g < 2; g++) {
      bf16x8 afr[4];
#pragma unroll
      for (int i = 0; i < 4; i++) {
        const int ar = wm * 64 + i * 16 + lrow;
        afr[i] = *(const bf16x8*)&As[g * 4096 + (ar * 4 + (quad ^ ((ar >> 1) & 3))) * 8];
      }
#pragma unroll
      for (int jh = 0; jh < 2; jh++) {
        bf16x8 bfr[4];
#pragma unroll
        for (int j = 0; j < 4; j++) {
          const int br = wn * 128 + (jh * 4 + j) * 16 + lrow;
          bfr[j] = *(const bf16x8*)&Bs[g * 8192 + (br * 4 + (quad ^ ((br >> 1) & 3))) * 8];
        }
#pragma unroll
        for (int i = 0; i < 4; i++)
#pragma unroll
          for (int j = 0; j < 4; j++)
            acc[i][jh * 4 + j] = __builtin_amdgcn_mfma_f32_16x16x32_bf16(
                afr[i], bfr[j], acc[i][jh * 4 + j], 0, 0, 0);
      }
    }
  }

  float bj[8];
#pragma unroll
  for (int j = 0; j < 8; j++) bj[j] = bias[n0 + wn * 128 + j * 16 + lrow];
#pragma unroll
  for (int i = 0; i < 4; i++) {
#pragma unroll
    for (int j = 0; j < 8; j++) {
      const int gcol = n0 + wn * 128 + j * 16 + lrow;
      const int hh = gcol >> 6, e = gcol & 63;
#pragma unroll
      for (int r = 0; r < 4; r++) {
        const int grow = m0 + wm * 64 + i * 16 + quad * 4 + r;
        const int bb = grow >> 10, l = grow & 1023;
        thb[(((size_t)bb * H_ + hh) * L_ + l) * HD_ + e] = f2bf(acc[i][j][r] + bj[j]);
      }
    }
  }
}

// ---------------------------------------------------------------------------
// K2: fp32 GEMM for the small d-projection (keeps dproj exact for ctx_t).
// ---------------------------------------------------------------------------
__global__ __launch_bounds__(256) void gemm_bias_kernel(
    const float* __restrict__ A, const float* __restrict__ W,
    const float* __restrict__ bias, float* __restrict__ C,
    int M, int K, int Nd) {
  __shared__ float As[8][132];
  __shared__ float Bs[8][132];
  const int tid = threadIdx.x;
  const int m0 = blockIdx.y * 128, n0 = blockIdx.x * 128;
  const int lr = tid >> 1, lc = (tid & 1) * 4;
  const int wr = tid >> 5, wc = (tid & 31) * 4;
  const int tm = (tid >> 4) * 4, tn = (tid & 15) * 4;

  float acc[2][2][4][4];
#pragma unroll
  for (int a = 0; a < 2; a++)
#pragma unroll
    for (int bq = 0; bq < 2; bq++)
#pragma unroll
      for (int i = 0; i < 4; i++)
#pragma unroll
        for (int j = 0; j < 4; j++) acc[a][bq][i][j] = 0.f;

  const float* Aptr = A + (size_t)(m0 + lr) * K + lc;
  const float* Wptr = W + (size_t)wr * Nd + n0 + wc;

  for (int k0 = 0; k0 < K; k0 += 8) {
    float4 a4 = *(const float4*)(Aptr + k0);
    float4 w4 = *(const float4*)(Wptr + (size_t)k0 * Nd);
    __syncthreads();
    As[lc+0][lr] = a4.x; As[lc+1][lr] = a4.y; As[lc+2][lr] = a4.z; As[lc+3][lr] = a4.w;
    *(float4*)&Bs[wr][wc] = w4;
    __syncthreads();
#pragma unroll
    for (int kk = 0; kk < 8; kk++) {
      float4 a0 = *(const float4*)&As[kk][tm];
      float4 a1 = *(const float4*)&As[kk][tm + 64];
      float4 b0 = *(const float4*)&Bs[kk][tn];
      float4 b1 = *(const float4*)&Bs[kk][tn + 64];
      const float av0[4] = {a0.x, a0.y, a0.z, a0.w};
      const float av1[4] = {a1.x, a1.y, a1.z, a1.w};
      const float bv0[4] = {b0.x, b0.y, b0.z, b0.w};
      const float bv1[4] = {b1.x, b1.y, b1.z, b1.w};
#pragma unroll
      for (int i = 0; i < 4; i++)
#pragma unroll
        for (int j = 0; j < 4; j++) {
          acc[0][0][i][j] += av0[i] * bv0[j];
          acc[0][1][i][j] += av0[i] * bv1[j];
          acc[1][0][i][j] += av1[i] * bv0[j];
          acc[1][1][i][j] += av1[i] * bv1[j];
        }
    }
  }
  float4 bias0 = *(const float4*)&bias[n0 + tn];
  float4 bias1 = *(const float4*)&bias[n0 + tn + 64];
  const float bb0[4] = {bias0.x, bias0.y, bias0.z, bias0.w};
  const float bb1[4] = {bias1.x, bias1.y, bias1.z, bias1.w};
#pragma unroll
  for (int mh = 0; mh < 2; mh++)
#pragma unroll
    for (int i = 0; i < 4; i++) {
      const int row = m0 + mh * 64 + tm + i;
      float* cp = C + (size_t)row * Nd + n0;
      float4 o0, o1;
      o0.x = acc[mh][0][i][0] + bb0[0]; o0.y = acc[mh][0][i][1] + bb0[1];
      o0.z = acc[mh][0][i][2] + bb0[2]; o0.w = acc[mh][0][i][3] + bb0[3];
      o1.x = acc[mh][1][i][0] + bb1[0]; o1.y = acc[mh][1][i][1] + bb1[1];
      o1.z = acc[mh][1][i][2] + bb1[2]; o1.w = acc[mh][1][i][3] + bb1[3];
      *(float4*)(cp + tn) = o0;
      *(float4*)(cp + tn + 64) = o1;
    }
}

// ---------------------------------------------------------------------------
// K3: dWb[b][h][n][e] = (dh @ Wb[h]) in bf16. grid = 256 (hb = b*8+h).
// dproj slice staged in LDS (coalesced float4); wb reads as float4.
// ---------------------------------------------------------------------------
__global__ __launch_bounds__(256) void dw_kernel(
    const float* __restrict__ dproj, const float* __restrict__ Wb,
    unsigned short* __restrict__ dWb) {
  __shared__ float wb_s[64 * 64];    // 16 KB
  __shared__ float dp_s[128 * 64];   // 32 KB
  const int tid = threadIdx.x;
  const int hb = blockIdx.x, b = hb >> 3, h = hb & 7;
  for (int i = tid; i < 4096; i += 256) wb_s[i] = Wb[(size_t)h * 4096 + i];
#pragma unroll
  for (int rep = 0; rep < 8; rep++) {   // 2048 float4 loads, 16 threads/row
    const int idx = rep * 256 + tid;
    const int row = idx >> 4, c4 = (idx & 15) * 4;
    *(float4*)&dp_s[row * 64 + c4] =
        *(const float4*)&dproj[((size_t)(b * N_ + row)) * HID_ + h * HD_ + c4];
  }
  __syncthreads();
  const int n = tid >> 1, half = tid & 1;
  float acc[32];
#pragma unroll
  for (int e = 0; e < 32; e++) acc[e] = 0.f;
  const float* dpr = &dp_s[n * 64];
  for (int k = 0; k < 64; k++) {
    const float a = dpr[k];   // 2 threads share addr -> LDS broadcast
    const float* wr = &wb_s[k * 64 + half * 32];
#pragma unroll
    for (int e4 = 0; e4 < 8; e4++) {
      float4 w = *(const float4*)&wr[e4 * 4];
      acc[e4*4+0] += a * w.x; acc[e4*4+1] += a * w.y;
      acc[e4*4+2] += a * w.z; acc[e4*4+3] += a * w.w;
    }
  }
  unsigned short* outp = dWb + ((size_t)hb * N_ + n) * HD_ + half * 32;
#pragma unroll
  for (int e = 0; e < 32; e++) outp[e] = f2bf(acc[e]);
}

// ---------------------------------------------------------------------------
// S-tile (128n x 64l) via MFMA, operands from global bf16 head-major arrays;
// masked fp32 S to LDS (stride 69: conflict-light on row and column walks).
// ---------------------------------------------------------------------------
__device__ __forceinline__ void mfma_S_tile(
    const unsigned short* __restrict__ thp, const unsigned short* __restrict__ dwp,
    float* __restrict__ S_s, int ncnt, int lv, int tid) {
  const int lane = tid & 63, wave = tid >> 6;
  const int quad = lane >> 4, lr = lane & 15;
  const int noff = (wave & 1) * 64, loff = (wave >> 1) * 32;

  floatx4 acc[4][2];
#pragma unroll
  for (int i = 0; i < 4; i++)
#pragma unroll
    for (int j = 0; j < 2; j++) acc[i][j] = (floatx4){0.f, 0.f, 0.f, 0.f};

#pragma unroll
  for (int kc = 0; kc < 2; kc++) {
    bf16x8 bfr[2];
#pragma unroll
    for (int j = 0; j < 2; j++)
      bfr[j] = *(const bf16x8*)&thp[(size_t)(loff + j * 16 + lr) * HD_ + kc * 32 + quad * 8];
#pragma unroll
    for (int i = 0; i < 4; i++) {
      bf16x8 afr = *(const bf16x8*)&dwp[(size_t)(noff + i * 16 + lr) * HD_ + kc * 32 + quad * 8];
#pragma unroll
      for (int j = 0; j < 2; j++)
        acc[i][j] = __builtin_amdgcn_mfma_f32_16x16x32_bf16(afr, bfr[j], acc[i][j], 0, 0, 0);
    }
  }
#pragma unroll
  for (int i = 0; i < 4; i++)
#pragma unroll
    for (int j = 0; j < 2; j++)
#pragma unroll
      for (int r = 0; r < 4; r++) {
        const int n = noff + i * 16 + quad * 4 + r;
        const int li = loff + j * 16 + lr;
        const bool ok = (n < ncnt) && (li < lv);
        S_s[n * 69 + li] = ok ? acc[i][j][r] : -1e9f;
      }
}

// ---------------------------------------------------------------------------
// K4: per (hb, lt): S tile -> column softmax (complete per tile); per-tile
// row stats (m_t, z_t) and per-tile w partial (no atomics). grid = 256*16.
// n-loops capped at block-uniform ncnt (rows >= ncnt contribute exactly 0).
// ---------------------------------------------------------------------------
__global__ __launch_bounds__(256, 4) void attn_stats_kernel(
    const unsigned short* __restrict__ thb, const unsigned short* __restrict__ dWb,
    const int* __restrict__ cnts, float* __restrict__ rwt,
    float* __restrict__ rmt, float* __restrict__ rzt) {
  __shared__ float S_s[128 * 69];
  __shared__ float red[256];
  __shared__ float zb_s[256], wb_s[256];
  __shared__ float cm_s[64], ics_s[64];
  const int tid = threadIdx.x;
  const int hb = blockIdx.x >> 4, lt = blockIdx.x & 15;
  const int b = hb >> 3;
  const int ncnt = cnts[b * 2], lcnt = cnts[b * 2 + 1];
  const int l0g = lt * 64;
  if (l0g >= lcnt) return;
  const int lv = min(64, lcnt - l0g);

  mfma_S_tile(thb + ((size_t)hb * L_ + l0g) * HD_, dWb + (size_t)hb * N_ * HD_,
              S_s, ncnt, lv, tid);
  __syncthreads();

  {  // column max partials (over valid n only)
    const int l = tid & 63, q = tid >> 6;
    const int ne = min(q * 32 + 32, ncnt);
    float pm = -INFINITY;
    for (int n = q * 32; n < ne; n++) pm = fmaxf(pm, S_s[n * 69 + l]);
    red[tid] = pm;
  }
  __syncthreads();
  if (tid < 64)
    cm_s[tid] = fmaxf(fmaxf(red[tid], red[tid + 64]), fmaxf(red[tid + 128], red[tid + 192]));
  __syncthreads();
  {  // column expsum partials (valid n only)
    const int l = tid & 63, q = tid >> 6;
    const int ne = min(q * 32 + 32, ncnt);
    const float cm = cm_s[l];
    float ps = 0.f;
    for (int n = q * 32; n < ne; n++) ps += __expf(S_s[n * 69 + l] - cm);
    red[tid] = ps;
  }
  __syncthreads();
  if (tid < 64)
    ics_s[tid] = 1.f / (red[tid] + red[tid + 64] + red[tid + 128] + red[tid + 192]);
  __syncthreads();
  {  // row pass, split across halves: n = tid&127, half covers 32 l's
    const int n = tid & 127, half = tid >> 7;
    const float* Sr = &S_s[n * 69];
    const int lb = half * 32, le = min(lb + 32, lv);
    float tmax = -INFINITY;
    for (int l = lb; l < le; l++) tmax = fmaxf(tmax, Sr[l]);
    red[tid] = tmax;
    __syncthreads();
    const float tm = fmaxf(red[n], red[n + 128]);
    float z = 0.f, w = 0.f;
    for (int l = lb; l < le; l++) {
      const float s = Sr[l];
      z += __expf(s - tm);
      w += __expf(s - cm_s[l]) * ics_s[l];
    }
    zb_s[tid] = z; wb_s[tid] = w;
    __syncthreads();
    if (tid < 128) {
      const size_t o = ((size_t)hb * 16 + lt) * 128 + tid;
      rmt[o] = tm;
      rzt[o] = zb_s[tid] + zb_s[tid + 128];
      rwt[o] = wb_s[tid] + wb_s[tid + 128];
    }
  }
}

// ---------------------------------------------------------------------------
// K5: combine per-tile row stats -> (m, 1/Z) and w; finalize ctx_t. grid=256.
// ---------------------------------------------------------------------------
__global__ __launch_bounds__(256) void attn_combine_kernel(
    const float* __restrict__ rmt, const float* __restrict__ rzt,
    const float* __restrict__ rwt, const float* __restrict__ dproj,
    const int* __restrict__ cnts, float* __restrict__ rm_g,
    float* __restrict__ riz_g, float* __restrict__ outp) {
  __shared__ float red[256];
  __shared__ float w_s[128];
  const int tid = threadIdx.x;
  const int hb = blockIdx.x, b = hb >> 3, h = hb & 7;
  const int ncnt = cnts[b * 2], lcnt = cnts[b * 2 + 1];
  const int ntl = (lcnt + 63) >> 6;
  if (tid < 128) {
    const int n = tid;
    float m = -INFINITY;
    for (int t = 0; t < ntl; t++)
      m = fmaxf(m, rmt[((size_t)hb * 16 + t) * 128 + n]);
    float Z = 0.f, w = 0.f;
    for (int t = 0; t < ntl; t++) {
      const size_t o = ((size_t)hb * 16 + t) * 128 + n;
      Z += rzt[o] * __expf(rmt[o] - m);
      w += rwt[o];
    }
    rm_g[hb * 128 + n] = m;
    riz_g[hb * 128 + n] = (n < ncnt) ? 1.f / Z : 0.f;
    w_s[n] = (n < ncnt) ? w : 0.f;
  }
  __syncthreads();
  const int e = tid & 63, q = tid >> 6;
  float p = 0.f;
  const int nb = q * 32, ne = min(nb + 32, ncnt);
  for (int n = nb; n < ne; n++)
    p += w_s[n] * dproj[((size_t)(b * N_ + n)) * HID_ + h * HD_ + e];
  red[tid] = p;
  __syncthreads();
  if (tid < 64) {
    const float s = red[tid] + red[tid + 64] + red[tid + 128] + red[tid + 192];
    outp[(size_t)b * (2 * HID_) + HID_ + h * HD_ + tid] = s / (float)lcnt;
  }
}

// ---------------------------------------------------------------------------
// K6: recompute S tile; v[l] = sum_n exp(S-m[n])/Z[n]; fused ctx_d partial
// accumulation (atomicAdd into zero-initialized out). grid = 256*16.
// n-loop capped at ncnt (riz=0 beyond -> identical); l-loop capped at lv.
// ---------------------------------------------------------------------------
__global__ __launch_bounds__(256, 4) void attn_v_kernel(
    const unsigned short* __restrict__ thb, const unsigned short* __restrict__ dWb,
    const int* __restrict__ cnts, const float* __restrict__ rm_g,
    const float* __restrict__ riz_g, float* __restrict__ outp) {
  __shared__ float S_s[128 * 69];
  __shared__ float red[256];
  __shared__ float rm_s[128], riz_s[128], v_s[64];
  const int tid = threadIdx.x;
  const int hb = blockIdx.x >> 4, lt = blockIdx.x & 15;
  const int b = hb >> 3, h = hb & 7;
  const int ncnt = cnts[b * 2], lcnt = cnts[b * 2 + 1];
  const int l0g = lt * 64;
  if (l0g >= lcnt) return;
  const int lv = min(64, lcnt - l0g);

  if (tid < 128) {
    rm_s[tid] = rm_g[hb * 128 + tid];
    riz_s[tid] = riz_g[hb * 128 + tid];
  }
  const unsigned short* thp = thb + ((size_t)hb * L_ + l0g) * HD_;
  mfma_S_tile(thp, dWb + (size_t)hb * N_ * HD_, S_s, ncnt, lv, tid);
  __syncthreads();

  {
    const int l = tid & 63, q = tid >> 6;
    const int ne = min(q * 32 + 32, ncnt);
    float vp = 0.f;
    for (int n = q * 32; n < ne; n++)
      vp += __expf(S_s[n * 69 + l] - rm_s[n]) * riz_s[n];
    red[tid] = vp;
  }
  __syncthreads();
  const float incnt = 1.f / (float)ncnt;
  if (tid < 64) {
    const float v = (tid < lv)
        ? (red[tid] + red[tid + 64] + red[tid + 128] + red[tid + 192]) * incnt
        : 0.f;
    v_s[tid] = v;
  }
  __syncthreads();
  {  // fused ctx_d partial: sum_{l in tile} v[l] * th[l][e]
    const int e = tid & 63, q = tid >> 6;
    const int le = min(q * 16 + 16, lv);
    float p = 0.f;
    for (int l = q * 16; l < le; l++)
      p += v_s[l] * bf2f(thp[(size_t)l * HD_ + e]);
    red[tid] = p;
  }
  __syncthreads();
  if (tid < 64) {
    const float s = red[tid] + red[tid + 64] + red[tid + 128] + red[tid + 192];
    if (s != 0.f)
      atomicAdd(&outp[(size_t)b * (2 * HID_) + h * HD_ + tid], s);
  }
}

// ---------------------------------------------------------------------------
extern "C" void kernel_launch(void* const* d_in, const int* in_sizes, int n_in,
                              void* d_out, int out_size, void* d_ws, size_t ws_size,
                              hipStream_t stream) {
  const float* drug = (const float*)d_in[0];
  const int* dmask = (const int*)d_in[1];
  const float* tseq = (const float*)d_in[2];
  const int* tmask = (const int*)d_in[3];
  const float* Wd = (const float*)d_in[4];
  const float* bd = (const float*)d_in[5];
  const float* Wt = (const float*)d_in[6];
  const float* bt = (const float*)d_in[7];
  const float* Wb = (const float*)d_in[8];
  float* out = (float*)d_out;
  float* ws = (float*)d_ws;

  float* dp = ws + WS_D;
  float* rm = ws + WS_RM;
  float* riz = ws + WS_RIZ;
  float* rmt = ws + WS_RMT;
  float* rzt = ws + WS_RZT;
  float* rwt = ws + WS_RWT;
  int* cnts = (int*)(ws + WS_CNT);
  unsigned short* wtT = (unsigned short*)(ws + WS_WT);
  unsigned short* thb = (unsigned short*)(ws + WS_THB);
  unsigned short* dWb = (unsigned short*)(ws + WS_DWB);

  count_kernel<<<B_, 256, 0, stream>>>(dmask, tmask, cnts);
  hipMemsetAsync(out, 0, (size_t)out_size * sizeof(float), stream);
  transpose_bf16_kernel<<<dim3(HID_ / 32, TD_ / 32), 256, 0, stream>>>(Wt, wtT, TD_, HID_);
  gemm_t_mfma_kernel<<<(HID_ / 256) * ((B_ * L_) / 128), 256, 0, stream>>>(
      tseq, wtT, bt, thb, TD_);
  gemm_bias_kernel<<<dim3(HID_ / 128, (B_ * N_) / 128), 256, 0, stream>>>(
      drug, Wd, bd, dp, B_ * N_, DD_, HID_);
  dw_kernel<<<B_ * H_, 256, 0, stream>>>(dp, Wb, dWb);
  attn_stats_kernel<<<B_ * H_ * 16, 256, 0, stream>>>(thb, dWb, cnts, rwt, rmt, rzt);
  attn_combine_kernel<<<B_ * H_, 256, 0, stream>>>(rmt, rzt, rwt, dp, cnts, rm, riz, out);
  attn_v_kernel<<<B_ * H_ * 16, 256, 0, stream>>>(thb, dWb, cnts, rm, riz, out);
}

// Round 9
// 428.100 us; speedup vs baseline: 1.0818x; 1.0558x over previous
//
#include <hip/hip_runtime.h>
#include <hip/hip_bf16.h>
#include <math.h>

#define B_ 32
#define N_ 128
#define L_ 1024
#define DD_ 256
#define TD_ 1280
#define HID_ 512
#define H_ 8
#define HD_ 64

// ws layout (float offsets)
#define WS_D    0
#define WS_RM   (WS_D   + 2097152)
#define WS_RIZ  (WS_RM  + 32768)
#define WS_RMT  (WS_RIZ + 32768)
#define WS_RZT  (WS_RMT + 524288)
#define WS_RWT  (WS_RZT + 524288)
#define WS_CNT  (WS_RWT + 524288)
#define WS_WT   (WS_CNT + 64)
#define WS_THB  (WS_WT  + 327680)
#define WS_DWB  (WS_THB + 8388608)

using bf16x8 = __attribute__((ext_vector_type(8))) short;
using u16x4 = __attribute__((ext_vector_type(4))) unsigned short;
using floatx4 = __attribute__((ext_vector_type(4))) float;

static __device__ __forceinline__ unsigned short f2bf(float f) {
  unsigned int u = __float_as_uint(f);
  unsigned int r = (u + 0x7FFFu + ((u >> 16) & 1u)) >> 16;
  return (unsigned short)r;
}
static __device__ __forceinline__ float bf2f(unsigned short s) {
  return __uint_as_float(((unsigned int)s) << 16);
}
// async global->LDS DMA, 16 B per lane; LDS dest = wave-uniform base + lane*16.
static __device__ __forceinline__ void gload16(const void* g, void* l) {
  __builtin_amdgcn_global_load_lds(
      (const __attribute__((address_space(1))) void*)g,
      (__attribute__((address_space(3))) void*)l, 16, 0, 0);
}

// ---------------------------------------------------------------------------
// K0: per-batch valid counts (detect int32 vs packed-bool at runtime).
// ---------------------------------------------------------------------------
__global__ __launch_bounds__(256) void count_kernel(const int* __restrict__ dmask,
                                                    const int* __restrict__ tmask,
                                                    int* __restrict__ cnts) {
  __shared__ int red[256];
  const int b = blockIdx.x, tid = threadIdx.x;
  const bool dint = (dmask[0] == 1);
  const bool tint = (tmask[0] == 1);
  int s = 0;
  if (dint) {
    for (int i = tid; i < N_; i += 256) s += (dmask[(size_t)b*N_ + i] != 0);
  } else {
    const unsigned char* p = (const unsigned char*)dmask;
    for (int i = tid; i < N_; i += 256) s += (p[(size_t)b*N_ + i] != 0);
  }
  red[tid] = s; __syncthreads();
  for (int off = 128; off > 0; off >>= 1) { if (tid < off) red[tid] += red[tid+off]; __syncthreads(); }
  if (tid == 0) cnts[b*2] = red[0];
  __syncthreads();
  s = 0;
  if (tint) {
    for (int i = tid; i < L_; i += 256) s += (tmask[(size_t)b*L_ + i] != 0);
  } else {
    const unsigned char* p = (const unsigned char*)tmask;
    for (int i = tid; i < L_; i += 256) s += (p[(size_t)b*L_ + i] != 0);
  }
  red[tid] = s; __syncthreads();
  for (int off = 128; off > 0; off >>= 1) { if (tid < off) red[tid] += red[tid+off]; __syncthreads(); }
  if (tid == 0) cnts[b*2+1] = red[0];
}

// ---------------------------------------------------------------------------
// K0b: W (KxN fp32) -> WT (NxK bf16), 32x32 LDS tiles.
// ---------------------------------------------------------------------------
__global__ __launch_bounds__(256) void transpose_bf16_kernel(
    const float* __restrict__ W, unsigned short* __restrict__ WT, int K, int Nd) {
  __shared__ float tile[32][33];
  const int tid = threadIdx.x;
  const int n0 = blockIdx.x * 32, k0 = blockIdx.y * 32;
  const int c = tid & 31, r0 = tid >> 5;
#pragma unroll
  for (int i = 0; i < 4; i++) {
    const int r = r0 + i * 8;
    tile[c][r] = W[(size_t)(k0 + r) * Nd + n0 + c];
  }
  __syncthreads();
#pragma unroll
  for (int i = 0; i < 4; i++) {
    const int r = r0 + i * 8;
    WT[(size_t)(n0 + r) * K + k0 + c] = f2bf(tile[r][c]);
  }
}

// ---------------------------------------------------------------------------
// K1: t-projection, fused fp32->bf16. ROUND-5 EXACT config (best measured):
// BM=128 x BN=256, 4 waves, acc[4][8], single Bs buffer, 48 KB LDS.
// ---------------------------------------------------------------------------
__global__ __launch_bounds__(256, 2) void gemm_t_mfma_kernel(
    const float* __restrict__ A, const unsigned short* __restrict__ WT,
    const float* __restrict__ bias, unsigned short* __restrict__ thb, int K) {
  __shared__ __align__(16) unsigned short As[8192];    // 128 rows x 64 k
  __shared__ __align__(16) unsigned short Bs[16384];   // 256 rows x 64 k
  const int tid = threadIdx.x;
  const int lin = blockIdx.x;
  const int xcd = lin & 7, sq = lin >> 3;
  const int n_t = sq & 1, m_t = (sq >> 1) + xcd * 32;
  const int m0 = m_t * 128, n0 = n_t * 256;
  const int lane = tid & 63, wave = tid >> 6;
  const int wm = wave & 1, wn = wave >> 1;
  const int quad = lane >> 4, lrow = lane & 15;

  floatx4 acc[4][8];
#pragma unroll
  for (int i = 0; i < 4; i++)
#pragma unroll
    for (int j = 0; j < 8; j++) acc[i][j] = (floatx4){0.f, 0.f, 0.f, 0.f};

  // B staging source offsets (four calls x two kgroups; 256 rows)
  int srcoffB[4][2];
#pragma unroll
  for (int call = 0; call < 4; call++) {
    const int i = call * 256 + tid;
    const int r = i >> 2;
    const int c = (i & 3) ^ ((r >> 1) & 3);
#pragma unroll
    for (int g = 0; g < 2; g++) srcoffB[call][g] = r * K + g * 32 + c * 8;
  }

  // A staging map (coalesced): instr i covers rows i*16 + arow_ (4 rows/wave),
  // lane's 16-lane group spans one row's 64 contiguous floats.
  const int arow_ = wave * 4 + (lane >> 4);   // base row 0..15
  const int x_ = lane & 15;                    // 16-B column slot (x_*4 floats)
  const int ag_ = x_ >> 3;                     // kgroup 0/1
  const int acq_ = (x_ & 7) >> 1;              // 8-col chunk within group
  const int ahalf_ = x_ & 1;                   // half-slot (4 shorts)

  const float* Abase = A + (size_t)m0 * K;
  const unsigned short* Bbase = WT + (size_t)n0 * K;

  float4 apf[8];

  auto aload = [&](int k0) {
#pragma unroll
    for (int i = 0; i < 8; i++)
      apf[i] = *(const float4*)(Abase + (size_t)(i * 16 + arow_) * K + k0 + x_ * 4);
  };
  auto awrite = [&]() {
#pragma unroll
    for (int i = 0; i < 8; i++) {
      const int r = i * 16 + arow_;
      const int sw = (r >> 1) & 3;
      u16x4 p;
      p[0] = f2bf(apf[i].x); p[1] = f2bf(apf[i].y);
      p[2] = f2bf(apf[i].z); p[3] = f2bf(apf[i].w);
      *(u16x4*)&As[ag_ * 4096 + (r * 4 + (acq_ ^ sw)) * 8 + ahalf_ * 4] = p;
    }
  };
  auto bstage = [&](int k0) {
#pragma unroll
    for (int g = 0; g < 2; g++)
#pragma unroll
      for (int call = 0; call < 4; call++) {
        const int dst = g * 8192 + (call * 256 + wave * 64) * 8;
        gload16(Bbase + k0 + srcoffB[call][g], &Bs[dst]);
      }
  };

  const int nkt = K / 64;   // 20
  aload(0);

  for (int t = 0; t < nkt; t++) {
    __syncthreads();        // all waves done with As/Bs(t-1); drains apf loads
    bstage(t * 64);         // B DMA issue (8 gload16)
    awrite();               // As <- cvt(apf); apf older than DMA in vmcnt FIFO
    __syncthreads();        // drains B DMA; As/Bs(t) visible
    if (t + 1 < nkt) aload((t + 1) * 64);   // in flight across MFMA phase
#pragma unroll
    for (int g = 0; g < 2; g++) {
      bf16x8 afr[4];
#pragma unroll
      for (int i = 0; i < 4; i++) {
        const int ar = wm * 64 + i * 16 + lrow;
        afr[i] = *(const bf16x8*)&As[g * 4096 + (ar * 4 + (quad ^ ((ar >> 1) & 3))) * 8];
      }
#pragma unroll
      for (int jh = 0; jh < 2; jh++) {
        bf16x8 bfr[4];
#pragma unroll
        for (int j = 0; j < 4; j++) {
          const int br = wn * 128 + (jh * 4 + j) * 16 + lrow;
          bfr[j] = *(const bf16x8*)&Bs[g * 8192 + (br * 4 + (quad ^ ((br >> 1) & 3))) * 8];
        }
#pragma unroll
        for (int i = 0; i < 4; i++)
#pragma unroll
          for (int j = 0; j < 4; j++)
            acc[i][jh * 4 + j] = __builtin_amdgcn_mfma_f32_16x16x32_bf16(
                afr[i], bfr[j], acc[i][jh * 4 + j], 0, 0, 0);
      }
    }
  }

  float bj[8];
#pragma unroll
  for (int j = 0; j < 8; j++) bj[j] = bias[n0 + wn * 128 + j * 16 + lrow];
#pragma unroll
  for (int i = 0; i < 4; i++) {
#pragma unroll
    for (int j = 0; j < 8; j++) {
      const int gcol = n0 + wn * 128 + j * 16 + lrow;
      const int hh = gcol >> 6, e = gcol & 63;
#pragma unroll
      for (int r = 0; r < 4; r++) {
        const int grow = m0 + wm * 64 + i * 16 + quad * 4 + r;
        const int bb = grow >> 10, l = grow & 1023;
        thb[(((size_t)bb * H_ + hh) * L_ + l) * HD_ + e] = f2bf(acc[i][j][r] + bj[j]);
      }
    }
  }
}

// ---------------------------------------------------------------------------
// K2: fp32 GEMM for the small d-projection (keeps dproj exact for ctx_t).
// ---------------------------------------------------------------------------
__global__ __launch_bounds__(256) void gemm_bias_kernel(
    const float* __restrict__ A, const float* __restrict__ W,
    const float* __restrict__ bias, float* __restrict__ C,
    int M, int K, int Nd) {
  __shared__ float As[8][132];
  __shared__ float Bs[8][132];
  const int tid = threadIdx.x;
  const int m0 = blockIdx.y * 128, n0 = blockIdx.x * 128;
  const int lr = tid >> 1, lc = (tid & 1) * 4;
  const int wr = tid >> 5, wc = (tid & 31) * 4;
  const int tm = (tid >> 4) * 4, tn = (tid & 15) * 4;

  float acc[2][2][4][4];
#pragma unroll
  for (int a = 0; a < 2; a++)
#pragma unroll
    for (int bq = 0; bq < 2; bq++)
#pragma unroll
      for (int i = 0; i < 4; i++)
#pragma unroll
        for (int j = 0; j < 4; j++) acc[a][bq][i][j] = 0.f;

  const float* Aptr = A + (size_t)(m0 + lr) * K + lc;
  const float* Wptr = W + (size_t)wr * Nd + n0 + wc;

  for (int k0 = 0; k0 < K; k0 += 8) {
    float4 a4 = *(const float4*)(Aptr + k0);
    float4 w4 = *(const float4*)(Wptr + (size_t)k0 * Nd);
    __syncthreads();
    As[lc+0][lr] = a4.x; As[lc+1][lr] = a4.y; As[lc+2][lr] = a4.z; As[lc+3][lr] = a4.w;
    *(float4*)&Bs[wr][wc] = w4;
    __syncthreads();
#pragma unroll
    for (int kk = 0; kk < 8; kk++) {
      float4 a0 = *(const float4*)&As[kk][tm];
      float4 a1 = *(const float4*)&As[kk][tm + 64];
      float4 b0 = *(const float4*)&Bs[kk][tn];
      float4 b1 = *(const float4*)&Bs[kk][tn + 64];
      const float av0[4] = {a0.x, a0.y, a0.z, a0.w};
      const float av1[4] = {a1.x, a1.y, a1.z, a1.w};
      const float bv0[4] = {b0.x, b0.y, b0.z, b0.w};
      const float bv1[4] = {b1.x, b1.y, b1.z, b1.w};
#pragma unroll
      for (int i = 0; i < 4; i++)
#pragma unroll
        for (int j = 0; j < 4; j++) {
          acc[0][0][i][j] += av0[i] * bv0[j];
          acc[0][1][i][j] += av0[i] * bv1[j];
          acc[1][0][i][j] += av1[i] * bv0[j];
          acc[1][1][i][j] += av1[i] * bv1[j];
        }
    }
  }
  float4 bias0 = *(const float4*)&bias[n0 + tn];
  float4 bias1 = *(const float4*)&bias[n0 + tn + 64];
  const float bb0[4] = {bias0.x, bias0.y, bias0.z, bias0.w};
  const float bb1[4] = {bias1.x, bias1.y, bias1.z, bias1.w};
#pragma unroll
  for (int mh = 0; mh < 2; mh++)
#pragma unroll
    for (int i = 0; i < 4; i++) {
      const int row = m0 + mh * 64 + tm + i;
      float* cp = C + (size_t)row * Nd + n0;
      float4 o0, o1;
      o0.x = acc[mh][0][i][0] + bb0[0]; o0.y = acc[mh][0][i][1] + bb0[1];
      o0.z = acc[mh][0][i][2] + bb0[2]; o0.w = acc[mh][0][i][3] + bb0[3];
      o1.x = acc[mh][1][i][0] + bb1[0]; o1.y = acc[mh][1][i][1] + bb1[1];
      o1.z = acc[mh][1][i][2] + bb1[2]; o1.w = acc[mh][1][i][3] + bb1[3];
      *(float4*)(cp + tn) = o0;
      *(float4*)(cp + tn + 64) = o1;
    }
}

// ---------------------------------------------------------------------------
// K3: dWb[b][h][n][e] = (dh @ Wb[h]) in bf16. grid = 256 (hb = b*8+h).
// dproj slice staged in LDS (coalesced float4); wb reads as float4.
// ---------------------------------------------------------------------------
__global__ __launch_bounds__(256) void dw_kernel(
    const float* __restrict__ dproj, const float* __restrict__ Wb,
    unsigned short* __restrict__ dWb) {
  __shared__ float wb_s[64 * 64];    // 16 KB
  __shared__ float dp_s[128 * 64];   // 32 KB
  const int tid = threadIdx.x;
  const int hb = blockIdx.x, b = hb >> 3, h = hb & 7;
  for (int i = tid; i < 4096; i += 256) wb_s[i] = Wb[(size_t)h * 4096 + i];
#pragma unroll
  for (int rep = 0; rep < 8; rep++) {   // 2048 float4 loads, 16 threads/row
    const int idx = rep * 256 + tid;
    const int row = idx >> 4, c4 = (idx & 15) * 4;
    *(float4*)&dp_s[row * 64 + c4] =
        *(const float4*)&dproj[((size_t)(b * N_ + row)) * HID_ + h * HD_ + c4];
  }
  __syncthreads();
  const int n = tid >> 1, half = tid & 1;
  float acc[32];
#pragma unroll
  for (int e = 0; e < 32; e++) acc[e] = 0.f;
  const float* dpr = &dp_s[n * 64];
  for (int k = 0; k < 64; k++) {
    const float a = dpr[k];   // 2 threads share addr -> LDS broadcast
    const float* wr = &wb_s[k * 64 + half * 32];
#pragma unroll
    for (int e4 = 0; e4 < 8; e4++) {
      float4 w = *(const float4*)&wr[e4 * 4];
      acc[e4*4+0] += a * w.x; acc[e4*4+1] += a * w.y;
      acc[e4*4+2] += a * w.z; acc[e4*4+3] += a * w.w;
    }
  }
  unsigned short* outp = dWb + ((size_t)hb * N_ + n) * HD_ + half * 32;
#pragma unroll
  for (int e = 0; e < 32; e++) outp[e] = f2bf(acc[e]);
}

// ---------------------------------------------------------------------------
// S-tile (128n x 64l) via MFMA, operands from global bf16 head-major arrays;
// masked fp32 S to LDS (stride 69: conflict-light on row and column walks).
// ---------------------------------------------------------------------------
__device__ __forceinline__ void mfma_S_tile(
    const unsigned short* __restrict__ thp, const unsigned short* __restrict__ dwp,
    float* __restrict__ S_s, int ncnt, int lv, int tid) {
  const int lane = tid & 63, wave = tid >> 6;
  const int quad = lane >> 4, lr = lane & 15;
  const int noff = (wave & 1) * 64, loff = (wave >> 1) * 32;

  floatx4 acc[4][2];
#pragma unroll
  for (int i = 0; i < 4; i++)
#pragma unroll
    for (int j = 0; j < 2; j++) acc[i][j] = (floatx4){0.f, 0.f, 0.f, 0.f};

#pragma unroll
  for (int kc = 0; kc < 2; kc++) {
    bf16x8 bfr[2];
#pragma unroll
    for (int j = 0; j < 2; j++)
      bfr[j] = *(const bf16x8*)&thp[(size_t)(loff + j * 16 + lr) * HD_ + kc * 32 + quad * 8];
#pragma unroll
    for (int i = 0; i < 4; i++) {
      bf16x8 afr = *(const bf16x8*)&dwp[(size_t)(noff + i * 16 + lr) * HD_ + kc * 32 + quad * 8];
#pragma unroll
      for (int j = 0; j < 2; j++)
        acc[i][j] = __builtin_amdgcn_mfma_f32_16x16x32_bf16(afr, bfr[j], acc[i][j], 0, 0, 0);
    }
  }
#pragma unroll
  for (int i = 0; i < 4; i++)
#pragma unroll
    for (int j = 0; j < 2; j++)
#pragma unroll
      for (int r = 0; r < 4; r++) {
        const int n = noff + i * 16 + quad * 4 + r;
        const int li = loff + j * 16 + lr;
        const bool ok = (n < ncnt) && (li < lv);
        S_s[n * 69 + li] = ok ? acc[i][j][r] : -1e9f;
      }
}

// ---------------------------------------------------------------------------
// K4: per (hb, lt): S tile -> column softmax (complete per tile); per-tile
// row stats (m_t, z_t) and per-tile w partial (no atomics). grid = 256*16.
// ROUND-5 form: constant-trip loops (full unroll + batched LDS loads);
// masked rows read -1e9 and contribute exp-underflow zeros -- cheaper than
// runtime bounds that defeat unrolling (round-6 lesson).
// ---------------------------------------------------------------------------
__global__ __launch_bounds__(256, 4) void attn_stats_kernel(
    const unsigned short* __restrict__ thb, const unsigned short* __restrict__ dWb,
    const int* __restrict__ cnts, float* __restrict__ rwt,
    float* __restrict__ rmt, float* __restrict__ rzt) {
  __shared__ float S_s[128 * 69];
  __shared__ float red[256];
  __shared__ float zb_s[256], wb_s[256];
  __shared__ float cm_s[64], ics_s[64];
  const int tid = threadIdx.x;
  const int hb = blockIdx.x >> 4, lt = blockIdx.x & 15;
  const int b = hb >> 3;
  const int ncnt = cnts[b * 2], lcnt = cnts[b * 2 + 1];
  const int l0g = lt * 64;
  if (l0g >= lcnt) return;
  const int lv = min(64, lcnt - l0g);

  mfma_S_tile(thb + ((size_t)hb * L_ + l0g) * HD_, dWb + (size_t)hb * N_ * HD_,
              S_s, ncnt, lv, tid);
  __syncthreads();

  {  // column max partials (over n)
    const int l = tid & 63, q = tid >> 6;
    float pm = -INFINITY;
#pragma unroll
    for (int n = q * 32; n < q * 32 + 32; n++) pm = fmaxf(pm, S_s[n * 69 + l]);
    red[tid] = pm;
  }
  __syncthreads();
  if (tid < 64)
    cm_s[tid] = fmaxf(fmaxf(red[tid], red[tid + 64]), fmaxf(red[tid + 128], red[tid + 192]));
  __syncthreads();
  {  // column expsum partials
    const int l = tid & 63, q = tid >> 6;
    const float cm = cm_s[l];
    float ps = 0.f;
#pragma unroll
    for (int n = q * 32; n < q * 32 + 32; n++) ps += __expf(S_s[n * 69 + l] - cm);
    red[tid] = ps;
  }
  __syncthreads();
  if (tid < 64)
    ics_s[tid] = 1.f / (red[tid] + red[tid + 64] + red[tid + 128] + red[tid + 192]);
  __syncthreads();
  {  // row pass, split across halves: n = tid&127, half covers 32 l's
    const int n = tid & 127, half = tid >> 7;
    const float* Sr = &S_s[n * 69];
    const int lb = half * 32, le = min(lb + 32, lv);
    float tmax = -INFINITY;
    for (int l = lb; l < le; l++) tmax = fmaxf(tmax, Sr[l]);
    red[tid] = tmax;
    __syncthreads();
    const float tm = fmaxf(red[n], red[n + 128]);
    float z = 0.f, w = 0.f;
    for (int l = lb; l < le; l++) {
      const float s = Sr[l];
      z += __expf(s - tm);
      w += __expf(s - cm_s[l]) * ics_s[l];
    }
    zb_s[tid] = z; wb_s[tid] = w;
    __syncthreads();
    if (tid < 128) {
      const size_t o = ((size_t)hb * 16 + lt) * 128 + tid;
      rmt[o] = tm;
      rzt[o] = zb_s[tid] + zb_s[tid + 128];
      rwt[o] = wb_s[tid] + wb_s[tid + 128];
    }
  }
}

// ---------------------------------------------------------------------------
// K5: combine per-tile row stats -> (m, 1/Z) and w; finalize ctx_t. grid=256.
// ---------------------------------------------------------------------------
__global__ __launch_bounds__(256) void attn_combine_kernel(
    const float* __restrict__ rmt, const float* __restrict__ rzt,
    const float* __restrict__ rwt, const float* __restrict__ dproj,
    const int* __restrict__ cnts, float* __restrict__ rm_g,
    float* __restrict__ riz_g, float* __restrict__ outp) {
  __shared__ float red[256];
  __shared__ float w_s[128];
  const int tid = threadIdx.x;
  const int hb = blockIdx.x, b = hb >> 3, h = hb & 7;
  const int ncnt = cnts[b * 2], lcnt = cnts[b * 2 + 1];
  const int ntl = (lcnt + 63) >> 6;
  if (tid < 128) {
    const int n = tid;
    float m = -INFINITY;
    for (int t = 0; t < ntl; t++)
      m = fmaxf(m, rmt[((size_t)hb * 16 + t) * 128 + n]);
    float Z = 0.f, w = 0.f;
    for (int t = 0; t < ntl; t++) {
      const size_t o = ((size_t)hb * 16 + t) * 128 + n;
      Z += rzt[o] * __expf(rmt[o] - m);
      w += rwt[o];
    }
    rm_g[hb * 128 + n] = m;
    riz_g[hb * 128 + n] = (n < ncnt) ? 1.f / Z : 0.f;
    w_s[n] = (n < ncnt) ? w : 0.f;
  }
  __syncthreads();
  const int e = tid & 63, q = tid >> 6;
  float p = 0.f;
  const int nb = q * 32, ne = min(nb + 32, ncnt);
  for (int n = nb; n < ne; n++)
    p += w_s[n] * dproj[((size_t)(b * N_ + n)) * HID_ + h * HD_ + e];
  red[tid] = p;
  __syncthreads();
  if (tid < 64) {
    const float s = red[tid] + red[tid + 64] + red[tid + 128] + red[tid + 192];
    outp[(size_t)b * (2 * HID_) + HID_ + h * HD_ + tid] = s / (float)lcnt;
  }
}

// ---------------------------------------------------------------------------
// K6 (REWRITE): in-register column reduction -- no S_s LDS buffer.
// After MFMA, thread holds S[n][li] for n = noff+i*16+quad*4+r,
// li = loff+j*16+lr. v[li] = sum_n exp(S - m[n])*riz[n] is a column sum:
// 16 exps/thread + shfl_xor over quad bits (lane^16, lane^32) + 2x64 LDS
// cross-wave combine. LDS 35KB -> ~3.5KB; exp count halved; occupancy
// 4 -> 6 blocks/CU. Masks preserved exactly (n>=ncnt would be NaN: rm=-1e9).
// ---------------------------------------------------------------------------
__global__ __launch_bounds__(256, 6) void attn_v_kernel(
    const unsigned short* __restrict__ thb, const unsigned short* __restrict__ dWb,
    const int* __restrict__ cnts, const float* __restrict__ rm_g,
    const float* __restrict__ riz_g, float* __restrict__ outp) {
  __shared__ float rm_s[128], riz_s[128];
  __shared__ float v_part[2][64];
  __shared__ float v_s[64];
  __shared__ float red[256];
  const int tid = threadIdx.x;
  const int hb = blockIdx.x >> 4, lt = blockIdx.x & 15;
  const int b = hb >> 3, h = hb & 7;
  const int ncnt = cnts[b * 2], lcnt = cnts[b * 2 + 1];
  const int l0g = lt * 64;
  if (l0g >= lcnt) return;
  const int lv = min(64, lcnt - l0g);

  if (tid < 128) {
    rm_s[tid] = rm_g[hb * 128 + tid];
    riz_s[tid] = riz_g[hb * 128 + tid];
  }
  __syncthreads();

  const int lane = tid & 63, wave = tid >> 6;
  const int quad = lane >> 4, lr = lane & 15;
  const int noff = (wave & 1) * 64, loff = (wave >> 1) * 32;
  const unsigned short* thp = thb + ((size_t)hb * L_ + l0g) * HD_;
  const unsigned short* dwp = dWb + (size_t)hb * N_ * HD_;

  floatx4 acc[4][2];
#pragma unroll
  for (int i = 0; i < 4; i++)
#pragma unroll
    for (int j = 0; j < 2; j++) acc[i][j] = (floatx4){0.f, 0.f, 0.f, 0.f};
#pragma unroll
  for (int kc = 0; kc < 2; kc++) {
    bf16x8 bfr[2];
#pragma unroll
    for (int j = 0; j < 2; j++)
      bfr[j] = *(const bf16x8*)&thp[(size_t)(loff + j * 16 + lr) * HD_ + kc * 32 + quad * 8];
#pragma unroll
    for (int i = 0; i < 4; i++) {
      bf16x8 afr = *(const bf16x8*)&dwp[(size_t)(noff + i * 16 + lr) * HD_ + kc * 32 + quad * 8];
#pragma unroll
      for (int j = 0; j < 2; j++)
        acc[i][j] = __builtin_amdgcn_mfma_f32_16x16x32_bf16(afr, bfr[j], acc[i][j], 0, 0, 0);
    }
  }

  // per-thread column partials: vp[j] = sum over this thread's 16 n's
  float vp[2] = {0.f, 0.f};
  const bool lok0 = (loff + 0 * 16 + lr) < lv;
  const bool lok1 = (loff + 1 * 16 + lr) < lv;
#pragma unroll
  for (int i = 0; i < 4; i++) {
#pragma unroll
    for (int r = 0; r < 4; r++) {
      const int n = noff + i * 16 + quad * 4 + r;
      if (n < ncnt) {
        const float m = rm_s[n], rz = riz_s[n];
        if (lok0) vp[0] += __expf(acc[i][0][r] - m) * rz;
        if (lok1) vp[1] += __expf(acc[i][1][r] - m) * rz;
      }
    }
  }
  // butterfly over quad bits: lanes lane^16, lane^32 hold other n-quads, same li
#pragma unroll
  for (int j = 0; j < 2; j++) {
    vp[j] += __shfl_xor(vp[j], 16);
    vp[j] += __shfl_xor(vp[j], 32);
  }
  if (quad == 0) {
#pragma unroll
    for (int j = 0; j < 2; j++)
      v_part[wave & 1][loff + j * 16 + lr] = vp[j];
  }
  __syncthreads();
  const float incnt = 1.f / (float)ncnt;
  if (tid < 64)
    v_s[tid] = (tid < lv) ? (v_part[0][tid] + v_part[1][tid]) * incnt : 0.f;
  __syncthreads();

  {  // fused ctx_d partial: sum_{l in tile} v[l] * th[l][e]
    const int e = tid & 63, q = tid >> 6;
    float p = 0.f;
#pragma unroll
    for (int l = q * 16; l < q * 16 + 16; l++)
      p += v_s[l] * bf2f(thp[(size_t)l * HD_ + e]);
    red[tid] = p;
  }
  __syncthreads();
  if (tid < 64) {
    const float s = red[tid] + red[tid + 64] + red[tid + 128] + red[tid + 192];
    if (s != 0.f)
      atomicAdd(&outp[(size_t)b * (2 * HID_) + h * HD_ + tid], s);
  }
}

// ---------------------------------------------------------------------------
extern "C" void kernel_launch(void* const* d_in, const int* in_sizes, int n_in,
                              void* d_out, int out_size, void* d_ws, size_t ws_size,
                              hipStream_t stream) {
  const float* drug = (const float*)d_in[0];
  const int* dmask = (const int*)d_in[1];
  const float* tseq = (const float*)d_in[2];
  const int* tmask = (const int*)d_in[3];
  const float* Wd = (const float*)d_in[4];
  const float* bd = (const float*)d_in[5];
  const float* Wt = (const float*)d_in[6];
  const float* bt = (const float*)d_in[7];
  const float* Wb = (const float*)d_in[8];
  float* out = (float*)d_out;
  float* ws = (float*)d_ws;

  float* dp = ws + WS_D;
  float* rm = ws + WS_RM;
  float* riz = ws + WS_RIZ;
  float* rmt = ws + WS_RMT;
  float* rzt = ws + WS_RZT;
  float* rwt = ws + WS_RWT;
  int* cnts = (int*)(ws + WS_CNT);
  unsigned short* wtT = (unsigned short*)(ws + WS_WT);
  unsigned short* thb = (unsigned short*)(ws + WS_THB);
  unsigned short* dWb = (unsigned short*)(ws + WS_DWB);

  count_kernel<<<B_, 256, 0, stream>>>(dmask, tmask, cnts);
  hipMemsetAsync(out, 0, (size_t)out_size * sizeof(float), stream);
  transpose_bf16_kernel<<<dim3(HID_ / 32, TD_ / 32), 256, 0, stream>>>(Wt, wtT, TD_, HID_);
  gemm_t_mfma_kernel<<<(HID_ / 256) * ((B_ * L_) / 128), 256, 0, stream>>>(
      tseq, wtT, bt, thb, TD_);
  gemm_bias_kernel<<<dim3(HID_ / 128, (B_ * N_) / 128), 256, 0, stream>>>(
      drug, Wd, bd, dp, B_ * N_, DD_, HID_);
  dw_kernel<<<B_ * H_, 256, 0, stream>>>(dp, Wb, dWb);
  attn_stats_kernel<<<B_ * H_ * 16, 256, 0, stream>>>(thb, dWb, cnts, rwt, rmt, rzt);
  attn_combine_kernel<<<B_ * H_, 256, 0, stream>>>(rmt, rzt, rwt, dp, cnts, rm, riz, out);
  attn_v_kernel<<<B_ * H_ * 16, 256, 0, stream>>>(thb, dWb, cnts, rm, riz, out);
}